// Round 1
// baseline (816.488 us; speedup 1.0000x reference)
//
#include <hip/hip_runtime.h>
#include <hip/hip_bf16.h>
#include <math.h>

#define Hd   512
#define FPd  256
#define Ed   512
#define NFd  768
#define Ld   512
#define Bd   32
#define K2H  1024            // 2H
#define Nd   1024            // NF + FP
#define Md   (Ld * Bd)       // 16384

// ---------------------------------------------------------------------------
// Kernel 1: W_big[n][k]
//   n <  NF: sum_e F[n][e]    * W_feat[e][k]
//   n >= NF: sum_h v[n-NF][h] * W_lin[h][k]
// grid (k-tiles=8, n-tiles=32), block 256. Each block: 32 n x 128 k.
// ---------------------------------------------------------------------------
__global__ __launch_bounds__(256)
void build_wbig(const float* __restrict__ F,
                const float* __restrict__ Wf,
                const float* __restrict__ V,
                const float* __restrict__ Wl,
                float* __restrict__ Wbig) {
    __shared__ float fs[32][64];
    const int tid = threadIdx.x;
    const int n0  = blockIdx.y * 32;
    const int k   = blockIdx.x * 128 + (tid & 127);
    const int ty  = tid >> 7;   // 0..1 -> 16 rows each

    const float* src;  const float* wsrc;
    if (n0 < NFd) { src = F + (size_t)n0 * Ed;          wsrc = Wf; }
    else          { src = V + (size_t)(n0 - NFd) * Hd;  wsrc = Wl; }

    float acc[16];
#pragma unroll
    for (int i = 0; i < 16; i++) acc[i] = 0.f;

    for (int e0 = 0; e0 < 512; e0 += 64) {
#pragma unroll
        for (int rep = 0; rep < 2; rep++) {
            int idx = rep * 256 + tid;           // 0..511
            int i   = idx >> 4;                  // row 0..31
            int kq  = idx & 15;                  // quad 0..15
            float4 v4 = *(const float4*)(src + (size_t)i * 512 + e0 + kq * 4);
            *(float4*)(&fs[i][kq * 4]) = v4;
        }
        __syncthreads();
#pragma unroll 4
        for (int kk = 0; kk < 64; kk += 4) {
            float w0 = wsrc[(size_t)(e0 + kk + 0) * K2H + k];
            float w1 = wsrc[(size_t)(e0 + kk + 1) * K2H + k];
            float w2 = wsrc[(size_t)(e0 + kk + 2) * K2H + k];
            float w3 = wsrc[(size_t)(e0 + kk + 3) * K2H + k];
#pragma unroll
            for (int i = 0; i < 16; i++) {
                float4 f4 = *(const float4*)(&fs[ty * 16 + i][kk]);
                acc[i] += f4.x * w0 + f4.y * w1 + f4.z * w2 + f4.w * w3;
            }
        }
        __syncthreads();
    }
#pragma unroll
    for (int i = 0; i < 16; i++)
        Wbig[(size_t)(n0 + ty * 16 + i) * K2H + k] = acc[i];
}

// ---------------------------------------------------------------------------
// Kernel 1b: bias_big[n] = dot(F[n], b_feat)  or  dot(v[n-NF], b_lin)
// 1024 blocks x 64 threads (one wave per n).
// ---------------------------------------------------------------------------
__global__ __launch_bounds__(64)
void build_bias(const float* __restrict__ F, const float* __restrict__ bf,
                const float* __restrict__ V, const float* __restrict__ bl,
                float* __restrict__ bias) {
    const int n    = blockIdx.x;
    const int lane = threadIdx.x;
    const float* row; const float* bsrc;
    if (n < NFd) { row = F + (size_t)n * Ed;          bsrc = bf; }
    else         { row = V + (size_t)(n - NFd) * Hd;  bsrc = bl; }
    float a = 0.f;
#pragma unroll
    for (int rep = 0; rep < 8; rep++) {
        int e = rep * 64 + lane;
        a += row[e] * bsrc[e];
    }
#pragma unroll
    for (int off = 1; off < 64; off <<= 1) a += __shfl_xor(a, off);
    if (lane == 0) bias[n] = a;
}

// ---------------------------------------------------------------------------
// Kernel 2: fused GEMM + bias + softmax + transposed store.
// One block per (b, 16 consecutive l). energy tile 16 x 1024, K = 1024.
// Threads 256 = 4 waves; wave tr owns rows tr*4..tr*4+3.
// Col mapping per lane: n = cq*256 + tc*4 + j  (float4-able LDS reads).
// ---------------------------------------------------------------------------
#define TL 16
#define BK 8

__global__ __launch_bounds__(256)
void attn_fused(const float* __restrict__ enc,
                const float* __restrict__ Wbig,
                const float* __restrict__ bias,
                float* __restrict__ out) {
    __shared__ float a_s[BK][TL];
    __shared__ float b_s[BK][Nd];      // 32 KB
    __shared__ float bias_s[Nd];       // 4 KB

    const int tid = threadIdx.x;
    const int tc  = tid & 63;
    const int tr  = tid >> 6;          // wave id 0..3
    const int b   = blockIdx.x >> 5;   // 0..31
    const int l0  = (blockIdx.x & 31) * TL;

    {   // stage bias (covered by the K-loop's first __syncthreads)
        float4 v4 = *(const float4*)(bias + tid * 4);
        *(float4*)(&bias_s[tid * 4]) = v4;
    }

    float acc[4][16];
#pragma unroll
    for (int r = 0; r < 4; r++)
#pragma unroll
        for (int c = 0; c < 16; c++) acc[r][c] = 0.f;

    const float* aBase = enc + (size_t)l0 * (Bd * K2H) + (size_t)b * K2H;

    for (int k0 = 0; k0 < K2H; k0 += BK) {
        if (tid < 32) {                        // A tile: 16 rows x 8 k
            int i = tid >> 1, q = tid & 1;
            float4 v4 = *(const float4*)(aBase + (size_t)i * (Bd * K2H) + k0 + q * 4);
            a_s[q * 4 + 0][i] = v4.x;
            a_s[q * 4 + 1][i] = v4.y;
            a_s[q * 4 + 2][i] = v4.z;
            a_s[q * 4 + 3][i] = v4.w;
        }
#pragma unroll
        for (int rep = 0; rep < 8; rep++) {    // B tile: 1024 n x 8 k
            int idx = rep * 256 + tid;         // 0..2047
            int n = idx >> 1, q = idx & 1;
            float4 v4 = *(const float4*)(Wbig + (size_t)n * K2H + k0 + q * 4);
            b_s[q * 4 + 0][n] = v4.x;
            b_s[q * 4 + 1][n] = v4.y;
            b_s[q * 4 + 2][n] = v4.z;
            b_s[q * 4 + 3][n] = v4.w;
        }
        __syncthreads();
#pragma unroll
        for (int kk = 0; kk < BK; kk++) {
            float4 av = *(const float4*)(&a_s[kk][tr * 4]);
            float ar[4] = {av.x, av.y, av.z, av.w};
#pragma unroll
            for (int cq = 0; cq < 4; cq++) {
                float4 bv = *(const float4*)(&b_s[kk][cq * 256 + tc * 4]);
                float bc[4] = {bv.x, bv.y, bv.z, bv.w};
#pragma unroll
                for (int r = 0; r < 4; r++)
#pragma unroll
                    for (int j = 0; j < 4; j++)
                        acc[r][cq * 4 + j] += ar[r] * bc[j];
            }
        }
        __syncthreads();
    }

    // bias + softmax per row + transposed store
#pragma unroll
    for (int r = 0; r < 4; r++) {
        float e[16];
        float m = -INFINITY;
#pragma unroll
        for (int cq = 0; cq < 4; cq++) {
            float4 bv = *(const float4*)(&bias_s[cq * 256 + tc * 4]);
            float bc[4] = {bv.x, bv.y, bv.z, bv.w};
#pragma unroll
            for (int j = 0; j < 4; j++) {
                int c = cq * 4 + j;
                e[c] = acc[r][c] + bc[j];
                m = fmaxf(m, e[c]);
            }
        }
#pragma unroll
        for (int off = 1; off < 64; off <<= 1) m = fmaxf(m, __shfl_xor(m, off));
        float s = 0.f;
#pragma unroll
        for (int c = 0; c < 16; c++) { e[c] = __expf(e[c] - m); s += e[c]; }
#pragma unroll
        for (int off = 1; off < 64; off <<= 1) s += __shfl_xor(s, off);
        const float inv = 1.0f / s;

        const int l = l0 + tr * 4 + r;
        float* op = out + (size_t)b * (Nd * Ld) + l;
#pragma unroll
        for (int cq = 0; cq < 4; cq++)
#pragma unroll
            for (int j = 0; j < 4; j++) {
                int n = cq * 256 + tc * 4 + j;
                op[(size_t)n * Ld] = e[cq * 4 + j] * inv;
            }
    }
}

// ---------------------------------------------------------------------------
extern "C" void kernel_launch(void* const* d_in, const int* in_sizes, int n_in,
                              void* d_out, int out_size, void* d_ws, size_t ws_size,
                              hipStream_t stream) {
    (void)in_sizes; (void)n_in; (void)out_size; (void)ws_size;

    const float* F    = (const float*)d_in[0];   // (768, 512)
    const float* enc  = (const float*)d_in[1];   // (512, 32, 1024)
    const float* Wlin = (const float*)d_in[2];   // (512, 1024)
    const float* blin = (const float*)d_in[3];   // (512,)
    const float* Wfea = (const float*)d_in[4];   // (512, 1024)
    const float* bfea = (const float*)d_in[5];   // (512,)
    const float* V    = (const float*)d_in[6];   // (256, 512)
    float* out = (float*)d_out;                  // (32, 1024, 512)

    float* Wbig = (float*)d_ws;                         // 4 MB
    float* bias = (float*)((char*)d_ws + (size_t)Nd * K2H * sizeof(float));

    build_wbig<<<dim3(8, 32), 256, 0, stream>>>(F, Wfea, V, Wlin, Wbig);
    build_bias<<<dim3(1024), 64, 0, stream>>>(F, bfea, V, blin, bias);
    attn_fused<<<dim3(1024), 256, 0, stream>>>(enc, Wbig, bias, out);
}

// Round 3
// 243.206 us; speedup vs baseline: 3.3572x; 3.3572x over previous
//
#include <hip/hip_runtime.h>
#include <hip/hip_bf16.h>
#include <math.h>

#define Hd   512
#define FPd  256
#define Ed   512
#define NFd  768
#define Ld   512
#define Bd   32
#define K2H  1024            // 2H
#define Nd   1024            // NF + FP
#define Md   (Ld * Bd)       // 16384

typedef _Float16 f16x8  __attribute__((ext_vector_type(8)));
typedef float    f32x16 __attribute__((ext_vector_type(16)));

// ---------------------------------------------------------------------------
// Kernel 1: W_big[n][k] (fp32, [1024][1024])
//   n <  NF: sum_e F[n][e]    * W_feat[e][k]
//   n >= NF: sum_h v[n-NF][h] * W_lin[h][k]
// ---------------------------------------------------------------------------
__global__ __launch_bounds__(256)
void build_wbig(const float* __restrict__ F,
                const float* __restrict__ Wf,
                const float* __restrict__ V,
                const float* __restrict__ Wl,
                float* __restrict__ Wbig) {
    __shared__ float fs[32][64];
    const int tid = threadIdx.x;
    const int n0  = blockIdx.y * 32;
    const int k   = blockIdx.x * 128 + (tid & 127);
    const int ty  = tid >> 7;

    const float* src;  const float* wsrc;
    if (n0 < NFd) { src = F + (size_t)n0 * Ed;          wsrc = Wf; }
    else          { src = V + (size_t)(n0 - NFd) * Hd;  wsrc = Wl; }

    float acc[16];
#pragma unroll
    for (int i = 0; i < 16; i++) acc[i] = 0.f;

    for (int e0 = 0; e0 < 512; e0 += 64) {
#pragma unroll
        for (int rep = 0; rep < 2; rep++) {
            int idx = rep * 256 + tid;
            int i   = idx >> 4;
            int kq  = idx & 15;
            float4 v4 = *(const float4*)(src + (size_t)i * 512 + e0 + kq * 4);
            *(float4*)(&fs[i][kq * 4]) = v4;
        }
        __syncthreads();
#pragma unroll 4
        for (int kk = 0; kk < 64; kk += 4) {
            float w0 = wsrc[(size_t)(e0 + kk + 0) * K2H + k];
            float w1 = wsrc[(size_t)(e0 + kk + 1) * K2H + k];
            float w2 = wsrc[(size_t)(e0 + kk + 2) * K2H + k];
            float w3 = wsrc[(size_t)(e0 + kk + 3) * K2H + k];
#pragma unroll
            for (int i = 0; i < 16; i++) {
                float4 f4 = *(const float4*)(&fs[ty * 16 + i][kk]);
                acc[i] += f4.x * w0 + f4.y * w1 + f4.z * w2 + f4.w * w3;
            }
        }
        __syncthreads();
    }
#pragma unroll
    for (int i = 0; i < 16; i++)
        Wbig[(size_t)(n0 + ty * 16 + i) * K2H + k] = acc[i];
}

// ---------------------------------------------------------------------------
// Kernel 1b: bias_big[n]
// ---------------------------------------------------------------------------
__global__ __launch_bounds__(64)
void build_bias(const float* __restrict__ F, const float* __restrict__ bf,
                const float* __restrict__ V, const float* __restrict__ bl,
                float* __restrict__ bias) {
    const int n    = blockIdx.x;
    const int lane = threadIdx.x;
    const float* row; const float* bsrc;
    if (n < NFd) { row = F + (size_t)n * Ed;          bsrc = bf; }
    else         { row = V + (size_t)(n - NFd) * Hd;  bsrc = bl; }
    float a = 0.f;
#pragma unroll
    for (int rep = 0; rep < 8; rep++) {
        int e = rep * 64 + lane;
        a += row[e] * bsrc[e];
    }
#pragma unroll
    for (int off = 1; off < 64; off <<= 1) a += __shfl_xor(a, off);
    if (lane == 0) bias[n] = a;
}

// ---------------------------------------------------------------------------
// Kernel 2: repack Wbig fp32 -> fp16 hi/lo in MFMA B-fragment layout.
// frag index = ((nt*64 + ks)*64 + lane), each frag = 8 f16 (16B).
// n = nt*32 + (lane&31), k = ks*16 + (lane>>5)*8 + j.
// ---------------------------------------------------------------------------
__global__ __launch_bounds__(256)
void repack_b(const float* __restrict__ Wbig,
              _Float16* __restrict__ Bhi, _Float16* __restrict__ Blo) {
    const int gid  = blockIdx.x * 256 + threadIdx.x;   // 0..131071
    const int lane = gid & 63;
    const int ks   = (gid >> 6) & 63;
    const int nt   = gid >> 12;
    const int n = nt * 32 + (lane & 31);
    const int k = ks * 16 + (lane >> 5) * 8;
    const float* src = Wbig + (size_t)n * K2H + k;
    f16x8 h, l;
#pragma unroll
    for (int j = 0; j < 8; j++) {
        float a = src[j];
        _Float16 hh = (_Float16)a;
        h[j] = hh;
        l[j] = (_Float16)(a - (float)hh);
    }
    *(f16x8*)(Bhi + (size_t)gid * 8) = h;
    *(f16x8*)(Blo + (size_t)gid * 8) = l;
}

// ---------------------------------------------------------------------------
// Kernel 3: MFMA GEMM (fp16x3 split) + fused softmax -> probs f16 [m][n].
// 256 blocks x 512 thr (8 waves). Block: 64 m-rows x full N=1024.
// Wave wn owns cols wn*128..+127 (4 tiles of 32), rows: 2 msub of 32.
// A staged in XOR-swizzled LDS (reg-staged dbuf), B direct from L2 frags.
// ---------------------------------------------------------------------------
__global__ __launch_bounds__(512, 2)
void gemm_fused(const float* __restrict__ enc,
                const _Float16* __restrict__ Bhi,
                const _Float16* __restrict__ Blo,
                const float* __restrict__ bias,
                _Float16* __restrict__ probs) {
    __shared__ float As[64 * 64];
    __shared__ float red[8][64];
    __shared__ float redc[64];

    const int tid  = threadIdx.x;
    const int lane = tid & 63;
    const int wn   = tid >> 6;
    const int hf   = lane >> 5;
    const int l31  = lane & 31;
    const int m0   = blockIdx.x * 64;

    f32x16 acc[2][4];
#pragma unroll
    for (int a = 0; a < 2; a++)
#pragma unroll
        for (int b = 0; b < 4; b++)
#pragma unroll
            for (int r = 0; r < 16; r++) acc[a][b][r] = 0.f;

    // A staging mapping: thread -> (row = tid>>3, 8 consecutive k at (tid&7)*8)
    const int srow = tid >> 3, sk8 = tid & 7;
    const float* gA = enc + (size_t)(m0 + srow) * K2H + sk8 * 8;
    char* AsB = (char*)As;
    const uint32_t wb0 = (uint32_t)((srow * 256 + sk8 * 32)      ^ ((srow & 7) << 4));
    const uint32_t wb1 = (uint32_t)((srow * 256 + sk8 * 32 + 16) ^ ((srow & 7) << 4));

    {   // prologue: chunk 0
        float4 p0 = *(const float4*)gA;
        float4 p1 = *(const float4*)(gA + 4);
        *(float4*)(AsB + wb0) = p0;
        *(float4*)(AsB + wb1) = p1;
    }

    for (int c = 0; c < 16; c++) {
        float4 p0, p1;
        if (c < 15) {
            const float* g = gA + (c + 1) * 64;
            p0 = *(const float4*)g;
            p1 = *(const float4*)(g + 4);
        }
        __syncthreads();   // chunk c staged
#pragma unroll
        for (int ks = 0; ks < 4; ks++) {
            const int kk = c * 4 + ks;
            f16x8 ah[2], al[2];
#pragma unroll
            for (int ms = 0; ms < 2; ms++) {
                const int row = ms * 32 + l31;
                const uint32_t base = (uint32_t)(row * 256 + ks * 64 + hf * 32);
                const uint32_t sw   = (uint32_t)((row & 7) << 4);
                float4 a0 = *(const float4*)(AsB + (base ^ sw));
                float4 a1 = *(const float4*)(AsB + ((base + 16) ^ sw));
                float av[8] = {a0.x, a0.y, a0.z, a0.w, a1.x, a1.y, a1.z, a1.w};
#pragma unroll
                for (int j = 0; j < 8; j++) {
                    _Float16 hh = (_Float16)av[j];
                    ah[ms][j] = hh;
                    al[ms][j] = (_Float16)(av[j] - (float)hh);
                }
            }
#pragma unroll
            for (int nt = 0; nt < 4; nt++) {
                const size_t fo = ((size_t)((wn * 4 + nt) * 64 + kk) * 64 + lane) * 8;
                f16x8 bh = *(const f16x8*)(Bhi + fo);
                f16x8 bl = *(const f16x8*)(Blo + fo);
                acc[0][nt] = __builtin_amdgcn_mfma_f32_32x32x16_f16(ah[0], bh, acc[0][nt], 0, 0, 0);
                acc[1][nt] = __builtin_amdgcn_mfma_f32_32x32x16_f16(ah[1], bh, acc[1][nt], 0, 0, 0);
                acc[0][nt] = __builtin_amdgcn_mfma_f32_32x32x16_f16(al[0], bh, acc[0][nt], 0, 0, 0);
                acc[1][nt] = __builtin_amdgcn_mfma_f32_32x32x16_f16(al[1], bh, acc[1][nt], 0, 0, 0);
                acc[0][nt] = __builtin_amdgcn_mfma_f32_32x32x16_f16(ah[0], bl, acc[0][nt], 0, 0, 0);
                acc[1][nt] = __builtin_amdgcn_mfma_f32_32x32x16_f16(ah[1], bl, acc[1][nt], 0, 0, 0);
            }
        }
        __syncthreads();   // done reading chunk c
        if (c < 15) {
            *(float4*)(AsB + wb0) = p0;
            *(float4*)(AsB + wb1) = p1;
        }
    }

    // ---- epilogue: bias + softmax over N (cross-wave via LDS) ----
    float bv[4];
#pragma unroll
    for (int nt = 0; nt < 4; nt++) bv[nt] = bias[wn * 128 + nt * 32 + l31];
#pragma unroll
    for (int ms = 0; ms < 2; ms++)
#pragma unroll
        for (int nt = 0; nt < 4; nt++)
#pragma unroll
            for (int r = 0; r < 16; r++) acc[ms][nt][r] += bv[nt];

    // row max (C/D layout: col = lane&31, row = (r&3)+8*(r>>2)+4*hf)
#pragma unroll
    for (int ms = 0; ms < 2; ms++) {
#pragma unroll
        for (int r = 0; r < 16; r++) {
            float mx = fmaxf(fmaxf(acc[ms][0][r], acc[ms][1][r]),
                             fmaxf(acc[ms][2][r], acc[ms][3][r]));
#pragma unroll
            for (int off = 1; off < 32; off <<= 1) mx = fmaxf(mx, __shfl_xor(mx, off));
            const int rr = (r & 3) + 8 * (r >> 2) + 4 * hf;
            if (l31 == r) red[wn][ms * 32 + rr] = mx;
        }
    }
    __syncthreads();
    if (tid < 64) {
        float v = red[0][tid];
#pragma unroll
        for (int w = 1; w < 8; w++) v = fmaxf(v, red[w][tid]);
        redc[tid] = v;
    }
    __syncthreads();

    // exp + partial row sums
#pragma unroll
    for (int ms = 0; ms < 2; ms++) {
#pragma unroll
        for (int r = 0; r < 16; r++) {
            const int rr = (r & 3) + 8 * (r >> 2) + 4 * hf;
            const float rm = redc[ms * 32 + rr];
            float s = 0.f;
#pragma unroll
            for (int nt = 0; nt < 4; nt++) {
                float e = __expf(acc[ms][nt][r] - rm);
                acc[ms][nt][r] = e;
                s += e;
            }
#pragma unroll
            for (int off = 1; off < 32; off <<= 1) s += __shfl_xor(s, off);
            if (l31 == r) red[wn][ms * 32 + rr] = s;
        }
    }
    __syncthreads();
    if (tid < 64) {
        float v = 0.f;
#pragma unroll
        for (int w = 0; w < 8; w++) v += red[w][tid];
        redc[tid] = v;
    }
    __syncthreads();

    // normalize + store probs f16 [m][n] (coalesced)
#pragma unroll
    for (int ms = 0; ms < 2; ms++) {
#pragma unroll
        for (int r = 0; r < 16; r++) {
            const int rr  = (r & 3) + 8 * (r >> 2) + 4 * hf;
            const float inv = 1.0f / redc[ms * 32 + rr];
            const int m = m0 + ms * 32 + rr;
            _Float16* op = probs + (size_t)m * Nd + wn * 128 + l31;
#pragma unroll
            for (int nt = 0; nt < 4; nt++)
                op[nt * 32] = (_Float16)(acc[ms][nt][r] * inv);
        }
    }
}

// ---------------------------------------------------------------------------
// Kernel 4: transpose probs f16 [m=l*32+b][n] -> out fp32 [b][n][l]
// Block: (b, 32 l, 64 n) tile via LDS; full-128B-line stores.
// ---------------------------------------------------------------------------
__global__ __launch_bounds__(256)
void transpose_probs(const _Float16* __restrict__ probs, float* __restrict__ out) {
    __shared__ float t[64][33];
    const int tid = threadIdx.x;
    const int bid = blockIdx.x;
    const int b   = bid >> 8;          // 0..31
    const int lc  = (bid >> 4) & 15;   // l-chunk (32)
    const int nc  = bid & 15;          // n-chunk (64)
#pragma unroll
    for (int rep = 0; rep < 8; rep++) {
        int idx = rep * 256 + tid;     // 0..2047
        int r   = idx >> 6;            // l_local
        int cc  = idx & 63;            // n_local
        t[cc][r] = (float)probs[(size_t)((lc * 32 + r) * 32 + b) * Nd + nc * 64 + cc];
    }
    __syncthreads();
    const int nl = tid >> 2;           // 0..63
    const int lw = tid & 3;
    float* op = out + (size_t)b * (Nd * Ld) + (size_t)(nc * 64 + nl) * Ld + lc * 32;
    float4 o0 = make_float4(t[nl][lw * 8 + 0], t[nl][lw * 8 + 1],
                            t[nl][lw * 8 + 2], t[nl][lw * 8 + 3]);
    float4 o1 = make_float4(t[nl][lw * 8 + 4], t[nl][lw * 8 + 5],
                            t[nl][lw * 8 + 6], t[nl][lw * 8 + 7]);
    *(float4*)(op + lw * 8)     = o0;
    *(float4*)(op + lw * 8 + 4) = o1;
}

// ---------------------------------------------------------------------------
// Workspace layout (36.1 MB total):
//   probs f16 [16384][1024]  32 MB @ 0x0        (live: gemm_fused..transpose)
//   Wbig  f32 [1024][1024]    4 MB @ 0x0        (overlaps probs; dead after repack_b)
//   bias  f32 [1024]          4 KB @ 0x2000000
//   Bh    f16 [1M]            2 MB @ 0x2010000
//   Bl    f16 [1M]            2 MB @ 0x2210000
// ---------------------------------------------------------------------------
extern "C" void kernel_launch(void* const* d_in, const int* in_sizes, int n_in,
                              void* d_out, int out_size, void* d_ws, size_t ws_size,
                              hipStream_t stream) {
    (void)in_sizes; (void)n_in; (void)out_size; (void)ws_size;

    const float* F    = (const float*)d_in[0];   // (768, 512)
    const float* enc  = (const float*)d_in[1];   // (512, 32, 1024)
    const float* Wlin = (const float*)d_in[2];   // (512, 1024)
    const float* blin = (const float*)d_in[3];   // (512,)
    const float* Wfea = (const float*)d_in[4];   // (512, 1024)
    const float* bfea = (const float*)d_in[5];   // (512,)
    const float* V    = (const float*)d_in[6];   // (256, 512)
    float* out = (float*)d_out;                  // (32, 1024, 512)

    char* ws = (char*)d_ws;
    _Float16* probs = (_Float16*)ws;                   // 32 MB @ 0
    float*    Wbig  = (float*)ws;                      // 4 MB @ 0 (dead before probs written)
    float*    bias  = (float*)(ws + 0x2000000);        // 4 KB
    _Float16* Bh    = (_Float16*)(ws + 0x2010000);     // 2 MB
    _Float16* Bl    = (_Float16*)(ws + 0x2210000);     // 2 MB

    build_wbig<<<dim3(8, 32), 256, 0, stream>>>(F, Wfea, V, Wlin, Wbig);
    build_bias<<<dim3(1024), 64, 0, stream>>>(F, bfea, V, blin, bias);
    repack_b<<<dim3(512), 256, 0, stream>>>(Wbig, Bh, Bl);
    gemm_fused<<<dim3(256), 512, 0, stream>>>(enc, Bh, Bl, bias, probs);
    transpose_probs<<<dim3(8192), 256, 0, stream>>>(probs, out);
}